// Round 5
// baseline (373.624 us; speedup 1.0000x reference)
//
#include <hip/hip_runtime.h>

#define BB 8
#define CC 192
#define C2 384
#define HH 128
#define WW 128
#define NN 16384
#define NHEADS 4
#define HC 48
#define LTK 196   // LDS row stride in u16 (392 B, 8B-aligned rows; b64 frag reads)
#define LTK2 98   // same in u32

typedef float f32x4 __attribute__((ext_vector_type(4)));
typedef float f32x16 __attribute__((ext_vector_type(16)));
typedef short s16x4 __attribute__((ext_vector_type(4)));
typedef short s16x8 __attribute__((ext_vector_type(8)));
typedef unsigned short u16;
typedef u16 u16x4 __attribute__((ext_vector_type(4)));
typedef u16 u16x8 __attribute__((ext_vector_type(8)));
typedef unsigned int u32;

__device__ __forceinline__ float bfu2f(u32 u16v) {
  return __uint_as_float(u16v << 16);
}
__device__ __forceinline__ u16 f2bfu(float f) {
  u32 u = __float_as_uint(f);
  return (u16)((u + 0x7fffu + ((u >> 16) & 1u)) >> 16);
}
__device__ __forceinline__ s16x8 ldpair(const u16* p) {
  s16x4 lo = *reinterpret_cast<const s16x4*>(p);
  s16x4 hi = *reinterpret_cast<const s16x4*>(p + 16);
  return __builtin_shufflevector(lo, hi, 0, 1, 2, 3, 4, 5, 6, 7);
}
__device__ __forceinline__ s16x8 ldb64pair(const u32* p) {
  s16x4 lo = *reinterpret_cast<const s16x4*>(p);
  s16x4 hi = *reinterpret_cast<const s16x4*>(p + 2);
  return __builtin_shufflevector(lo, hi, 0, 1, 2, 3, 4, 5, 6, 7);
}

// ---------------------------------------------------------------------------
// K0a: w_qkv fp32 -> bf16
// ---------------------------------------------------------------------------
__global__ __launch_bounds__(256) void k0_wcvt(const float* __restrict__ w,
                                               u16* __restrict__ wbf) {
  const int i = (blockIdx.x * 256 + threadIdx.x) * 4;
  f32x4 v = *reinterpret_cast<const f32x4*>(&w[i]);
  u16x4 o;
  o[0] = f2bfu(v[0]); o[1] = f2bfu(v[1]); o[2] = f2bfu(v[2]); o[3] = f2bfu(v[3]);
  *reinterpret_cast<u16x4*>(&wbf[i]) = o;
}

// ---------------------------------------------------------------------------
// K1: qkv[b,o,n] = sum_c wbf[o,c] * x[b,c,n]. Stage x-panel (192c x 128n,
// fused f32->bf16, transposed [n][c]) into LDS ONCE; loop 3 o-tiles of 128
// with a barrier-free MFMA loop. 8 waves (2 o x 4 n), wave-tile 64o x 32n.
// grid (128, 8), 512 thr.
// ---------------------------------------------------------------------------
__global__ __launch_bounds__(512, 6) void k1_qkv(
    const float* __restrict__ x, const u16* __restrict__ wbf,
    u16* __restrict__ qkv) {
  const int n0 = blockIdx.x * 128;
  const int b  = blockIdx.y;
  __shared__ u16 Xs[128 * LTK];
  u32* Xsw = reinterpret_cast<u32*>(Xs);
  const int t = threadIdx.x, lane = t & 63;
  const int wid = t >> 6, wo = wid >> 2, wn = wid & 3;
  const int l31 = lane & 31, g2 = lane >> 5;

  // ---- stage x[c][n0..n0+127] -> Xs[n][c] (bf16), once ----
  {
    const int nq = t & 31, cr = t >> 5;        // cr 0..15
    const int kpb = cr >> 1;                   // u32 col base
    const int jb = (cr & 1) << 1;              // row duty: 0/1 vs 2/3
    const float* xb = x + (size_t)b * CC * NN + n0 + 4 * nq;
    #pragma unroll 4
    for (int i = 0; i < 12; ++i) {
      f32x4 v = *reinterpret_cast<const f32x4*>(xb + (size_t)(cr + 16 * i) * NN);
      u32 A  = (u32)f2bfu(v[0]) | ((u32)f2bfu(v[1]) << 16);
      u32 Bp = (u32)f2bfu(v[2]) | ((u32)f2bfu(v[3]) << 16);
      u32 oA = __shfl_xor(A, 32);
      u32 oB = __shfl_xor(Bp, 32);
      u32 va, vb;
      if (cr & 1) {
        va = (oB & 0xffffu) | (Bp << 16);
        vb = (oB >> 16) | (Bp & 0xffff0000u);
      } else {
        va = (A & 0xffffu) | (oA << 16);
        vb = (A >> 16) | (oA & 0xffff0000u);
      }
      const int col = kpb + 8 * i;
      Xsw[(4 * nq + jb) * LTK2 + col] = va;
      Xsw[(4 * nq + jb + 1) * LTK2 + col] = vb;
    }
  }
  __syncthreads();

  const int nloc = wn * 32 + l31;
  const int ncol = n0 + nloc;
  f32x16 acc[2];

  for (int ot = 0; ot < 3; ++ot) {
    const int o0 = ot * 128;
    #pragma unroll
    for (int mi = 0; mi < 2; ++mi)
      #pragma unroll
      for (int e = 0; e < 16; ++e) acc[mi][e] = 0.f;

    #pragma unroll
    for (int s = 0; s < 6; ++s) {
      s16x8 bf[2];
      #pragma unroll
      for (int h = 0; h < 2; ++h)
        bf[h] = ldb64pair(&Xsw[nloc * LTK2 + 16 * s + 8 * h + 4 * g2]);
      #pragma unroll
      for (int mi = 0; mi < 2; ++mi) {
        const int orow = o0 + wo * 64 + mi * 32 + l31;
        #pragma unroll
        for (int h = 0; h < 2; ++h) {
          s16x8 af = *reinterpret_cast<const s16x8*>(
              &wbf[(size_t)orow * CC + 32 * s + 16 * h + 8 * g2]);
          acc[mi] = __builtin_amdgcn_mfma_f32_32x32x16_bf16(af, bf[h], acc[mi], 0, 0, 0);
        }
      }
    }
    #pragma unroll
    for (int mi = 0; mi < 2; ++mi) {
      const int ob = o0 + wo * 64 + mi * 32;
      #pragma unroll
      for (int r = 0; r < 16; ++r) {
        const int row = (r & 3) + 8 * (r >> 2) + 4 * g2;
        qkv[((size_t)b * C2 + ob + row) * NN + ncol] = f2bfu(acc[mi][r]);
      }
    }
  }
}

// ---------------------------------------------------------------------------
// K2: 3x3 depthwise, 8 px/thread (unchanged).
// ---------------------------------------------------------------------------
__global__ __launch_bounds__(256) void k2_dw(
    const u16* __restrict__ qkv, const float* __restrict__ wdw,
    u16* __restrict__ out) {
  const int gid = blockIdx.x;
  const int rb = gid & 7;
  const int plane = gid >> 3;
  const int ch = plane % C2;
  const int t = threadIdx.x;
  const int row = rb * 16 + (t >> 4);
  const int x0 = (t & 15) * 8;
  const u16* p = qkv + (size_t)plane * NN;
  const float* wv = wdw + ch * 9;
  float o[8];
  #pragma unroll
  for (int j = 0; j < 8; ++j) o[j] = 0.f;
  #pragma unroll
  for (int dy = 0; dy < 3; ++dy) {
    const int yy = row + dy - 1;
    if ((unsigned)yy < (unsigned)HH) {
      const u16* rp = p + yy * WW;
      u16x8 m = *reinterpret_cast<const u16x8*>(&rp[x0]);
      float px[10];
      px[0] = (x0 > 0) ? bfu2f(rp[x0 - 1]) : 0.f;
      px[9] = (x0 < 120) ? bfu2f(rp[x0 + 8]) : 0.f;
      #pragma unroll
      for (int j = 0; j < 8; ++j) px[j + 1] = bfu2f(m[j]);
      const float w0 = wv[dy * 3 + 0], w1 = wv[dy * 3 + 1], w2 = wv[dy * 3 + 2];
      #pragma unroll
      for (int j = 0; j < 8; ++j)
        o[j] += w0 * px[j] + w1 * px[j + 1] + w2 * px[j + 2];
    }
  }
  u16x8 ov;
  #pragma unroll
  for (int j = 0; j < 8; ++j) ov[j] = f2bfu(o[j]);
  *reinterpret_cast<u16x8*>(&out[(size_t)plane * NN + row * WW + x0]) = ov;
}

// ---------------------------------------------------------------------------
// K3: partial Gram via MFMA (symmetric; same frag both operands).
// ---------------------------------------------------------------------------
__global__ __launch_bounds__(256) void k3_gram(
    const u16* __restrict__ qkvd, float* __restrict__ gpart) {
  const int bh = blockIdx.x, b = bh >> 2, h = bh & 3;
  const int chunk = blockIdx.y;
  const int t = threadIdx.x, lane = t & 63, wv = t >> 6;
  const int l15 = lane & 15, g = lane >> 4;
  __shared__ float red[4][2304];
  const u16* qb = qkvd + ((size_t)b * C2 + h * HC) * NN;

  f32x4 acc[3][3];
  #pragma unroll
  for (int i = 0; i < 3; ++i)
    #pragma unroll
    for (int j = 0; j < 3; ++j)
      #pragma unroll
      for (int e = 0; e < 4; ++e) acc[i][j][e] = 0.f;

  const int nbase = chunk * 1024 + wv * 256;
  #pragma unroll 2
  for (int st = 0; st < 8; ++st) {
    const int n = nbase + st * 32;
    s16x8 cf[3];
    #pragma unroll
    for (int i = 0; i < 3; ++i)
      cf[i] = ldpair(qb + (size_t)(i * 16 + l15) * NN + n + 4 * g);
    #pragma unroll
    for (int i = 0; i < 3; ++i)
      #pragma unroll
      for (int j = 0; j < 3; ++j)
        acc[i][j] = __builtin_amdgcn_mfma_f32_16x16x32_bf16(cf[i], cf[j], acc[i][j], 0, 0, 0);
  }
  #pragma unroll
  for (int i = 0; i < 3; ++i)
    #pragma unroll
    for (int j = 0; j < 3; ++j)
      #pragma unroll
      for (int r = 0; r < 4; ++r)
        red[wv][(i * 16 + 4 * g + r) * 48 + j * 16 + l15] = acc[i][j][r];
  __syncthreads();
  float* gp = gpart + ((size_t)bh * 16 + chunk) * 2304;
  for (int idx = t; idx < 2304; idx += 256)
    gp[idx] = red[0][idx] + red[1][idx] + red[2][idx] + red[3][idx];
}

// ---------------------------------------------------------------------------
// K4: reduce + normalize + softmax (unchanged)
// ---------------------------------------------------------------------------
__global__ __launch_bounds__(256) void k4_soft(
    const float* __restrict__ gpart, const float* __restrict__ temp,
    float* __restrict__ attn) {
  const int bh = blockIdx.x;
  const int h = bh & 3;
  const int t = threadIdx.x;
  __shared__ float G[2304];
  __shared__ float rn[48];
  for (int idx = t; idx < 2304; idx += 256) {
    float s = 0.f;
    #pragma unroll
    for (int c = 0; c < 16; ++c) s += gpart[((size_t)bh * 16 + c) * 2304 + idx];
    G[idx] = s;
  }
  __syncthreads();
  if (t < 48) rn[t] = rsqrtf(G[t * 48 + t]);
  __syncthreads();
  if (t < 48) {
    const float tm = temp[h];
    float v[48];
    float mx = -1e30f;
    #pragma unroll
    for (int j = 0; j < 48; ++j) {
      v[j] = G[t * 48 + j] * rn[t] * rn[j] * tm;
      mx = fmaxf(mx, v[j]);
    }
    float s = 0.f;
    #pragma unroll
    for (int j = 0; j < 48; ++j) { v[j] = expf(v[j] - mx); s += v[j]; }
    const float inv = 1.f / s;
    #pragma unroll
    for (int j = 0; j < 48; ++j)
      attn[(size_t)bh * 2304 + t * 48 + j] = v[j] * inv;
  }
}

// ---------------------------------------------------------------------------
// K5: M = w_proj x blockdiag(attn) -> bf16 (unchanged)
// ---------------------------------------------------------------------------
__global__ __launch_bounds__(192) void k5_M(
    const float* __restrict__ wproj, const float* __restrict__ attn,
    u16* __restrict__ Mbf) {
  const int o = blockIdx.x;
  const int b = blockIdx.y;
  const int d = threadIdx.x;
  const int h = d / HC, dl = d % HC;
  const float* wrow = wproj + o * CC + h * HC;
  const float* at = attn + ((size_t)(b * NHEADS + h)) * 2304;
  float s = 0.f;
  #pragma unroll
  for (int c = 0; c < HC; ++c) s = fmaf(wrow[c], at[c * HC + dl], s);
  Mbf[((size_t)b * CC + o) * CC + d] = f2bfu(s);
}

// ---------------------------------------------------------------------------
// K6: out[b,o,n] = sum_d Mbf[b,o,d] * v[b,d,n]. Stage v-panel (192d x 128n,
// transposed [n][d]) once; 3 o-tiles of 64; 8 waves (2 o x 4 n), 32o x 32n.
// grid (128, 8), 512 thr.
// ---------------------------------------------------------------------------
__global__ __launch_bounds__(512, 6) void k6_out(
    const u16* __restrict__ Mbf, const u16* __restrict__ qkvd,
    float* __restrict__ out) {
  const int n0 = blockIdx.x * 128;
  const int b  = blockIdx.y;
  __shared__ u16 Vs[128 * LTK];
  u32* Vsw = reinterpret_cast<u32*>(Vs);
  const int t = threadIdx.x, lane = t & 63;
  const int wid = t >> 6, wo = wid >> 2, wn = wid & 3;
  const int l31 = lane & 31, g2 = lane >> 5;

  // ---- stage v[d][n0..n0+127] -> Vs[n][d], once ----
  {
    const int nq = t & 31, cr = t >> 5;
    const int kpb = cr >> 1;
    const int jb = (cr & 1) << 1;
    const u16* vbp = qkvd + ((size_t)b * C2 + CC) * NN + n0 + 4 * nq;
    #pragma unroll 4
    for (int i = 0; i < 12; ++i) {
      u16x4 m = *reinterpret_cast<const u16x4*>(vbp + (size_t)(cr + 16 * i) * NN);
      u32 A  = (u32)m[0] | ((u32)m[1] << 16);
      u32 Bp = (u32)m[2] | ((u32)m[3] << 16);
      u32 oA = __shfl_xor(A, 32);
      u32 oB = __shfl_xor(Bp, 32);
      u32 va, vb;
      if (cr & 1) {
        va = (oB & 0xffffu) | (Bp << 16);
        vb = (oB >> 16) | (Bp & 0xffff0000u);
      } else {
        va = (A & 0xffffu) | (oA << 16);
        vb = (A >> 16) | (oA & 0xffff0000u);
      }
      const int col = kpb + 8 * i;
      Vsw[(4 * nq + jb) * LTK2 + col] = va;
      Vsw[(4 * nq + jb + 1) * LTK2 + col] = vb;
    }
  }
  __syncthreads();

  const int nloc = wn * 32 + l31;
  const int ncol = n0 + nloc;
  const u16* Ab = Mbf + (size_t)b * CC * CC;
  f32x16 acc;

  for (int ot = 0; ot < 3; ++ot) {
    const int o0 = ot * 64;
    #pragma unroll
    for (int e = 0; e < 16; ++e) acc[e] = 0.f;
    #pragma unroll
    for (int s = 0; s < 6; ++s) {
      const int orow = o0 + wo * 32 + l31;
      #pragma unroll
      for (int h = 0; h < 2; ++h) {
        s16x8 bf = ldb64pair(&Vsw[nloc * LTK2 + 16 * s + 8 * h + 4 * g2]);
        s16x8 af = *reinterpret_cast<const s16x8*>(
            &Ab[(size_t)orow * CC + 32 * s + 16 * h + 8 * g2]);
        acc = __builtin_amdgcn_mfma_f32_32x32x16_bf16(af, bf, acc, 0, 0, 0);
      }
    }
    const int ob = o0 + wo * 32;
    #pragma unroll
    for (int r = 0; r < 16; ++r) {
      const int row = (r & 3) + 8 * (r >> 2) + 4 * g2;
      out[((size_t)b * CC + ob + row) * NN + ncol] = acc[r];
    }
  }
}

// ---------------------------------------------------------------------------
extern "C" void kernel_launch(void* const* d_in, const int* in_sizes, int n_in,
                              void* d_out, int out_size, void* d_ws, size_t ws_size,
                              hipStream_t stream) {
  const float* x      = (const float*)d_in[0];
  const float* w_qkv  = (const float*)d_in[1];
  const float* w_dw   = (const float*)d_in[2];
  const float* w_proj = (const float*)d_in[3];
  const float* temp   = (const float*)d_in[4];
  float* out = (float*)d_out;

  const size_t OFF_QKV   = 0;               // bf16  8*384*16384 = 100,663,296
  const size_t OFF_QKVD  = 100663296ULL;    // bf16  same
  const size_t OFF_GPART = 201326592ULL;    // f32   32*16*2304  = 4,718,592
  const size_t OFF_ATTN  = 206045184ULL;    // f32   32*2304     = 294,912
  const size_t OFF_M     = 206340096ULL;    // bf16  8*192*192   = 589,824
  const size_t OFF_WBF   = 206929920ULL;    // bf16  384*192     = 147,456
  const size_t NEEDED    = 207077376ULL;
  if (ws_size < NEEDED) return;

  char* ws = (char*)d_ws;
  u16* qkv   = (u16*)(ws + OFF_QKV);
  u16* qkvd  = (u16*)(ws + OFF_QKVD);
  float* gpart = (float*)(ws + OFF_GPART);
  float* attn  = (float*)(ws + OFF_ATTN);
  u16* Mbf   = (u16*)(ws + OFF_M);
  u16* wbf   = (u16*)(ws + OFF_WBF);

  k0_wcvt<<<dim3(72), 256, 0, stream>>>(w_qkv, wbf);
  k1_qkv <<<dim3(128, 8), 512, 0, stream>>>(x, wbf, qkv);
  k2_dw  <<<dim3(BB * C2 * 8), 256, 0, stream>>>(qkv, w_dw, qkvd);
  k3_gram<<<dim3(BB * NHEADS, 16), 256, 0, stream>>>(qkvd, gpart);
  k4_soft<<<dim3(BB * NHEADS), 256, 0, stream>>>(gpart, temp, attn);
  k5_M   <<<dim3(CC, BB), 192, 0, stream>>>(w_proj, attn, Mbf);
  k6_out <<<dim3(128, 8), 512, 0, stream>>>(Mbf, qkvd, out);
}

// Round 6
// 236.854 us; speedup vs baseline: 1.5774x; 1.5774x over previous
//
#include <hip/hip_runtime.h>

#define BB 8
#define CC 192
#define C2 384
#define HH 128
#define WW 128
#define NN 16384
#define NHEADS 4
#define HC 48
#define LTK 196   // LDS row stride in u16 (392 B, 8B-aligned rows)
#define LTK2 98   // same in u32

typedef float f32x4 __attribute__((ext_vector_type(4)));
typedef float f32x16 __attribute__((ext_vector_type(16)));
typedef short s16x4 __attribute__((ext_vector_type(4)));
typedef short s16x8 __attribute__((ext_vector_type(8)));
typedef unsigned short u16;
typedef u16 u16x4 __attribute__((ext_vector_type(4)));
typedef u16 u16x8 __attribute__((ext_vector_type(8)));
typedef unsigned int u32;

__device__ __forceinline__ float bfu2f(u32 u16v) {
  return __uint_as_float(u16v << 16);
}
__device__ __forceinline__ u16 f2bfu(float f) {
  u32 u = __float_as_uint(f);
  return (u16)((u + 0x7fffu + ((u >> 16) & 1u)) >> 16);
}
__device__ __forceinline__ s16x8 ldpair(const u16* p) {
  s16x4 lo = *reinterpret_cast<const s16x4*>(p);
  s16x4 hi = *reinterpret_cast<const s16x4*>(p + 16);
  return __builtin_shufflevector(lo, hi, 0, 1, 2, 3, 4, 5, 6, 7);
}
__device__ __forceinline__ s16x8 ldb64pair(const u32* p) {
  s16x4 lo = *reinterpret_cast<const s16x4*>(p);
  s16x4 hi = *reinterpret_cast<const s16x4*>(p + 2);
  return __builtin_shufflevector(lo, hi, 0, 1, 2, 3, 4, 5, 6, 7);
}

// ---------------------------------------------------------------------------
// K0a: w_qkv fp32 -> bf16
// ---------------------------------------------------------------------------
__global__ __launch_bounds__(256) void k0_wcvt(const float* __restrict__ w,
                                               u16* __restrict__ wbf) {
  const int i = (blockIdx.x * 256 + threadIdx.x) * 4;
  f32x4 v = *reinterpret_cast<const f32x4*>(&w[i]);
  u16x4 o;
  o[0] = f2bfu(v[0]); o[1] = f2bfu(v[1]); o[2] = f2bfu(v[2]); o[3] = f2bfu(v[3]);
  *reinterpret_cast<u16x4*>(&wbf[i]) = o;
}

// ---------------------------------------------------------------------------
// K1: qkv[b,o,n] = sum_c wbf[o,c] * x[b,c,n]. Stage x-panel (192c x 128n,
// fused f32->bf16, transposed [n][c]) into LDS ONCE; loop 3 o-tiles of 128.
// 8 waves = 4o x 2n; wave-tile 32o x 64n (2 x 32n frags -> full 128B lines).
// A-frags register-prefetched one K-step ahead. grid (128, 8), 512 thr.
// ---------------------------------------------------------------------------
__global__ __launch_bounds__(512, 4) void k1_qkv(
    const float* __restrict__ x, const u16* __restrict__ wbf,
    u16* __restrict__ qkv) {
  const int n0 = blockIdx.x * 128;
  const int b  = blockIdx.y;
  __shared__ u16 Xs[128 * LTK];
  u32* Xsw = reinterpret_cast<u32*>(Xs);
  const int t = threadIdx.x, lane = t & 63;
  const int wid = t >> 6, wo = wid >> 1, wn = wid & 1;
  const int l31 = lane & 31, g2 = lane >> 5;

  // ---- stage x[c][n0..n0+127] -> Xs[n][c] (bf16), once ----
  {
    const int nq = t & 31, cr = t >> 5;
    const int kpb = cr >> 1;
    const int jb = (cr & 1) << 1;
    const float* xb = x + (size_t)b * CC * NN + n0 + 4 * nq;
    #pragma unroll 4
    for (int i = 0; i < 12; ++i) {
      f32x4 v = *reinterpret_cast<const f32x4*>(xb + (size_t)(cr + 16 * i) * NN);
      u32 A  = (u32)f2bfu(v[0]) | ((u32)f2bfu(v[1]) << 16);
      u32 Bp = (u32)f2bfu(v[2]) | ((u32)f2bfu(v[3]) << 16);
      u32 oA = __shfl_xor(A, 32);
      u32 oB = __shfl_xor(Bp, 32);
      u32 va, vb;
      if (cr & 1) {
        va = (oB & 0xffffu) | (Bp << 16);
        vb = (oB >> 16) | (Bp & 0xffff0000u);
      } else {
        va = (A & 0xffffu) | (oA << 16);
        vb = (A >> 16) | (oA & 0xffff0000u);
      }
      const int col = kpb + 8 * i;
      Xsw[(4 * nq + jb) * LTK2 + col] = va;
      Xsw[(4 * nq + jb + 1) * LTK2 + col] = vb;
    }
  }
  __syncthreads();

  const int nbase = wn * 64;
  const u32* brow0 = &Xsw[(nbase + l31) * LTK2 + 4 * g2];
  const u32* brow1 = &Xsw[(nbase + 32 + l31) * LTK2 + 4 * g2];

  for (int ot = 0; ot < 3; ++ot) {
    const int o0 = ot * 128;
    const u16* wr = wbf + (size_t)(o0 + wo * 32 + l31) * CC + 8 * g2;
    f32x16 acc0, acc1;
    #pragma unroll
    for (int e = 0; e < 16; ++e) { acc0[e] = 0.f; acc1[e] = 0.f; }

    s16x8 af0 = *reinterpret_cast<const s16x8*>(wr);
    s16x8 af1 = *reinterpret_cast<const s16x8*>(wr + 16);
    #pragma unroll
    for (int s = 0; s < 6; ++s) {
      s16x8 an0, an1;
      if (s < 5) {
        an0 = *reinterpret_cast<const s16x8*>(wr + (s + 1) * 32);
        an1 = *reinterpret_cast<const s16x8*>(wr + (s + 1) * 32 + 16);
      }
      s16x8 bf00 = ldb64pair(brow0 + 16 * s);
      s16x8 bf01 = ldb64pair(brow0 + 16 * s + 8);
      s16x8 bf10 = ldb64pair(brow1 + 16 * s);
      s16x8 bf11 = ldb64pair(brow1 + 16 * s + 8);
      acc0 = __builtin_amdgcn_mfma_f32_32x32x16_bf16(af0, bf00, acc0, 0, 0, 0);
      acc1 = __builtin_amdgcn_mfma_f32_32x32x16_bf16(af0, bf10, acc1, 0, 0, 0);
      acc0 = __builtin_amdgcn_mfma_f32_32x32x16_bf16(af1, bf01, acc0, 0, 0, 0);
      acc1 = __builtin_amdgcn_mfma_f32_32x32x16_bf16(af1, bf11, acc1, 0, 0, 0);
      af0 = an0; af1 = an1;
    }
    #pragma unroll
    for (int r = 0; r < 16; ++r) {
      const int row = (r & 3) + 8 * (r >> 2) + 4 * g2;
      u16* qp = qkv + ((size_t)b * C2 + o0 + wo * 32 + row) * NN + n0 + nbase + l31;
      qp[0]  = f2bfu(acc0[r]);
      qp[32] = f2bfu(acc1[r]);
    }
  }
}

// ---------------------------------------------------------------------------
// K2: 3x3 depthwise, 8 px/thread (unchanged).
// ---------------------------------------------------------------------------
__global__ __launch_bounds__(256) void k2_dw(
    const u16* __restrict__ qkv, const float* __restrict__ wdw,
    u16* __restrict__ out) {
  const int gid = blockIdx.x;
  const int rb = gid & 7;
  const int plane = gid >> 3;
  const int ch = plane % C2;
  const int t = threadIdx.x;
  const int row = rb * 16 + (t >> 4);
  const int x0 = (t & 15) * 8;
  const u16* p = qkv + (size_t)plane * NN;
  const float* wv = wdw + ch * 9;
  float o[8];
  #pragma unroll
  for (int j = 0; j < 8; ++j) o[j] = 0.f;
  #pragma unroll
  for (int dy = 0; dy < 3; ++dy) {
    const int yy = row + dy - 1;
    if ((unsigned)yy < (unsigned)HH) {
      const u16* rp = p + yy * WW;
      u16x8 m = *reinterpret_cast<const u16x8*>(&rp[x0]);
      float px[10];
      px[0] = (x0 > 0) ? bfu2f(rp[x0 - 1]) : 0.f;
      px[9] = (x0 < 120) ? bfu2f(rp[x0 + 8]) : 0.f;
      #pragma unroll
      for (int j = 0; j < 8; ++j) px[j + 1] = bfu2f(m[j]);
      const float w0 = wv[dy * 3 + 0], w1 = wv[dy * 3 + 1], w2 = wv[dy * 3 + 2];
      #pragma unroll
      for (int j = 0; j < 8; ++j)
        o[j] += w0 * px[j] + w1 * px[j + 1] + w2 * px[j + 2];
    }
  }
  u16x8 ov;
  #pragma unroll
  for (int j = 0; j < 8; ++j) ov[j] = f2bfu(o[j]);
  *reinterpret_cast<u16x8*>(&out[(size_t)plane * NN + row * WW + x0]) = ov;
}

// ---------------------------------------------------------------------------
// K3: partial Gram via MFMA (symmetric; same frag both operands).
// ---------------------------------------------------------------------------
__global__ __launch_bounds__(256) void k3_gram(
    const u16* __restrict__ qkvd, float* __restrict__ gpart) {
  const int bh = blockIdx.x, b = bh >> 2, h = bh & 3;
  const int chunk = blockIdx.y;
  const int t = threadIdx.x, lane = t & 63, wv = t >> 6;
  const int l15 = lane & 15, g = lane >> 4;
  __shared__ float red[4][2304];
  const u16* qb = qkvd + ((size_t)b * C2 + h * HC) * NN;

  f32x4 acc[3][3];
  #pragma unroll
  for (int i = 0; i < 3; ++i)
    #pragma unroll
    for (int j = 0; j < 3; ++j)
      #pragma unroll
      for (int e = 0; e < 4; ++e) acc[i][j][e] = 0.f;

  const int nbase = chunk * 1024 + wv * 256;
  #pragma unroll 2
  for (int st = 0; st < 8; ++st) {
    const int n = nbase + st * 32;
    s16x8 cf[3];
    #pragma unroll
    for (int i = 0; i < 3; ++i)
      cf[i] = ldpair(qb + (size_t)(i * 16 + l15) * NN + n + 4 * g);
    #pragma unroll
    for (int i = 0; i < 3; ++i)
      #pragma unroll
      for (int j = 0; j < 3; ++j)
        acc[i][j] = __builtin_amdgcn_mfma_f32_16x16x32_bf16(cf[i], cf[j], acc[i][j], 0, 0, 0);
  }
  #pragma unroll
  for (int i = 0; i < 3; ++i)
    #pragma unroll
    for (int j = 0; j < 3; ++j)
      #pragma unroll
      for (int r = 0; r < 4; ++r)
        red[wv][(i * 16 + 4 * g + r) * 48 + j * 16 + l15] = acc[i][j][r];
  __syncthreads();
  float* gp = gpart + ((size_t)bh * 16 + chunk) * 2304;
  for (int idx = t; idx < 2304; idx += 256)
    gp[idx] = red[0][idx] + red[1][idx] + red[2][idx] + red[3][idx];
}

// ---------------------------------------------------------------------------
// K4: reduce + normalize + softmax (unchanged)
// ---------------------------------------------------------------------------
__global__ __launch_bounds__(256) void k4_soft(
    const float* __restrict__ gpart, const float* __restrict__ temp,
    float* __restrict__ attn) {
  const int bh = blockIdx.x;
  const int h = bh & 3;
  const int t = threadIdx.x;
  __shared__ float G[2304];
  __shared__ float rn[48];
  for (int idx = t; idx < 2304; idx += 256) {
    float s = 0.f;
    #pragma unroll
    for (int c = 0; c < 16; ++c) s += gpart[((size_t)bh * 16 + c) * 2304 + idx];
    G[idx] = s;
  }
  __syncthreads();
  if (t < 48) rn[t] = rsqrtf(G[t * 48 + t]);
  __syncthreads();
  if (t < 48) {
    const float tm = temp[h];
    float v[48];
    float mx = -1e30f;
    #pragma unroll
    for (int j = 0; j < 48; ++j) {
      v[j] = G[t * 48 + j] * rn[t] * rn[j] * tm;
      mx = fmaxf(mx, v[j]);
    }
    float s = 0.f;
    #pragma unroll
    for (int j = 0; j < 48; ++j) { v[j] = expf(v[j] - mx); s += v[j]; }
    const float inv = 1.f / s;
    #pragma unroll
    for (int j = 0; j < 48; ++j)
      attn[(size_t)bh * 2304 + t * 48 + j] = v[j] * inv;
  }
}

// ---------------------------------------------------------------------------
// K5: M = w_proj x blockdiag(attn) -> bf16 (unchanged)
// ---------------------------------------------------------------------------
__global__ __launch_bounds__(192) void k5_M(
    const float* __restrict__ wproj, const float* __restrict__ attn,
    u16* __restrict__ Mbf) {
  const int o = blockIdx.x;
  const int b = blockIdx.y;
  const int d = threadIdx.x;
  const int h = d / HC, dl = d % HC;
  const float* wrow = wproj + o * CC + h * HC;
  const float* at = attn + ((size_t)(b * NHEADS + h)) * 2304;
  float s = 0.f;
  #pragma unroll
  for (int c = 0; c < HC; ++c) s = fmaf(wrow[c], at[c * HC + dl], s);
  Mbf[((size_t)b * CC + o) * CC + d] = f2bfu(s);
}

// ---------------------------------------------------------------------------
// K6: out[b,o,n] = sum_d Mbf[b,o,d] * v[b,d,n]. Stage v-panel once; 3 o-tiles
// of 64; 8 waves = 2o x 4n, wave-tile 32o x 32n. Two independent h-chains
// (accA/accB) + A-prefetch. f32 stores = full 128B lines. grid (128,8), 512t.
// ---------------------------------------------------------------------------
__global__ __launch_bounds__(512, 4) void k6_out(
    const u16* __restrict__ Mbf, const u16* __restrict__ qkvd,
    float* __restrict__ out) {
  const int n0 = blockIdx.x * 128;
  const int b  = blockIdx.y;
  __shared__ u16 Vs[128 * LTK];
  u32* Vsw = reinterpret_cast<u32*>(Vs);
  const int t = threadIdx.x, lane = t & 63;
  const int wid = t >> 6, wo = wid >> 2, wn = wid & 3;
  const int l31 = lane & 31, g2 = lane >> 5;

  // ---- stage v[d][n0..n0+127] -> Vs[n][d], once ----
  {
    const int nq = t & 31, cr = t >> 5;
    const int kpb = cr >> 1;
    const int jb = (cr & 1) << 1;
    const u16* vbp = qkvd + ((size_t)b * C2 + CC) * NN + n0 + 4 * nq;
    #pragma unroll 4
    for (int i = 0; i < 12; ++i) {
      u16x4 m = *reinterpret_cast<const u16x4*>(vbp + (size_t)(cr + 16 * i) * NN);
      u32 A  = (u32)m[0] | ((u32)m[1] << 16);
      u32 Bp = (u32)m[2] | ((u32)m[3] << 16);
      u32 oA = __shfl_xor(A, 32);
      u32 oB = __shfl_xor(Bp, 32);
      u32 va, vb;
      if (cr & 1) {
        va = (oB & 0xffffu) | (Bp << 16);
        vb = (oB >> 16) | (Bp & 0xffff0000u);
      } else {
        va = (A & 0xffffu) | (oA << 16);
        vb = (A >> 16) | (oA & 0xffff0000u);
      }
      const int col = kpb + 8 * i;
      Vsw[(4 * nq + jb) * LTK2 + col] = va;
      Vsw[(4 * nq + jb + 1) * LTK2 + col] = vb;
    }
  }
  __syncthreads();

  const int nloc = wn * 32 + l31;
  const u32* brow = &Vsw[nloc * LTK2 + 4 * g2];
  const u16* Ab = Mbf + (size_t)b * CC * CC;

  for (int ot = 0; ot < 3; ++ot) {
    const int o0 = ot * 64;
    const u16* ar = Ab + (size_t)(o0 + wo * 32 + l31) * CC + 8 * g2;
    f32x16 accA, accB;
    #pragma unroll
    for (int e = 0; e < 16; ++e) { accA[e] = 0.f; accB[e] = 0.f; }

    s16x8 af0 = *reinterpret_cast<const s16x8*>(ar);
    s16x8 af1 = *reinterpret_cast<const s16x8*>(ar + 16);
    #pragma unroll
    for (int s = 0; s < 6; ++s) {
      s16x8 an0, an1;
      if (s < 5) {
        an0 = *reinterpret_cast<const s16x8*>(ar + (s + 1) * 32);
        an1 = *reinterpret_cast<const s16x8*>(ar + (s + 1) * 32 + 16);
      }
      s16x8 bf0 = ldb64pair(brow + 16 * s);
      s16x8 bf1 = ldb64pair(brow + 16 * s + 8);
      accA = __builtin_amdgcn_mfma_f32_32x32x16_bf16(af0, bf0, accA, 0, 0, 0);
      accB = __builtin_amdgcn_mfma_f32_32x32x16_bf16(af1, bf1, accB, 0, 0, 0);
      af0 = an0; af1 = an1;
    }
    #pragma unroll
    for (int r = 0; r < 16; ++r) {
      const int row = (r & 3) + 8 * (r >> 2) + 4 * g2;
      out[((size_t)b * CC + o0 + wo * 32 + row) * NN + n0 + nloc] = accA[r] + accB[r];
    }
  }
}

// ---------------------------------------------------------------------------
extern "C" void kernel_launch(void* const* d_in, const int* in_sizes, int n_in,
                              void* d_out, int out_size, void* d_ws, size_t ws_size,
                              hipStream_t stream) {
  const float* x      = (const float*)d_in[0];
  const float* w_qkv  = (const float*)d_in[1];
  const float* w_dw   = (const float*)d_in[2];
  const float* w_proj = (const float*)d_in[3];
  const float* temp   = (const float*)d_in[4];
  float* out = (float*)d_out;

  const size_t OFF_QKV   = 0;               // bf16  8*384*16384 = 100,663,296
  const size_t OFF_QKVD  = 100663296ULL;    // bf16  same
  const size_t OFF_GPART = 201326592ULL;    // f32   32*16*2304  = 4,718,592
  const size_t OFF_ATTN  = 206045184ULL;    // f32   32*2304     = 294,912
  const size_t OFF_M     = 206340096ULL;    // bf16  8*192*192   = 589,824
  const size_t OFF_WBF   = 206929920ULL;    // bf16  384*192     = 147,456
  const size_t NEEDED    = 207077376ULL;
  if (ws_size < NEEDED) return;

  char* ws = (char*)d_ws;
  u16* qkv   = (u16*)(ws + OFF_QKV);
  u16* qkvd  = (u16*)(ws + OFF_QKVD);
  float* gpart = (float*)(ws + OFF_GPART);
  float* attn  = (float*)(ws + OFF_ATTN);
  u16* Mbf   = (u16*)(ws + OFF_M);
  u16* wbf   = (u16*)(ws + OFF_WBF);

  k0_wcvt<<<dim3(72), 256, 0, stream>>>(w_qkv, wbf);
  k1_qkv <<<dim3(128, 8), 512, 0, stream>>>(x, wbf, qkv);
  k2_dw  <<<dim3(BB * C2 * 8), 256, 0, stream>>>(qkv, w_dw, qkvd);
  k3_gram<<<dim3(BB * NHEADS, 16), 256, 0, stream>>>(qkvd, gpart);
  k4_soft<<<dim3(BB * NHEADS), 256, 0, stream>>>(gpart, temp, attn);
  k5_M   <<<dim3(CC, BB), 192, 0, stream>>>(w_proj, attn, Mbf);
  k6_out <<<dim3(128, 8), 512, 0, stream>>>(Mbf, qkvd, out);
}

// Round 7
// 213.216 us; speedup vs baseline: 1.7523x; 1.1109x over previous
//
#include <hip/hip_runtime.h>

#define BB 8
#define CC 192
#define C2 384
#define HH 128
#define WW 128
#define NN 16384
#define NHEADS 4
#define HC 48
#define LTK 196   // LDS row stride in u16 (392 B)
#define LTK2 98   // same in u32
// LDS physical row map: phys(n) = (n>>1) + 64*(n&1)  (de-interleave even/odd cols)

typedef float f32x4 __attribute__((ext_vector_type(4)));
typedef float f32x16 __attribute__((ext_vector_type(16)));
typedef short s16x4 __attribute__((ext_vector_type(4)));
typedef short s16x8 __attribute__((ext_vector_type(8)));
typedef unsigned short u16;
typedef u16 u16x4 __attribute__((ext_vector_type(4)));
typedef u16 u16x8 __attribute__((ext_vector_type(8)));
typedef unsigned int u32;

__device__ __forceinline__ float bfu2f(u32 u16v) {
  return __uint_as_float(u16v << 16);
}
__device__ __forceinline__ u16 f2bfu(float f) {
  u32 u = __float_as_uint(f);
  return (u16)((u + 0x7fffu + ((u >> 16) & 1u)) >> 16);
}
__device__ __forceinline__ s16x8 ldpair(const u16* p) {
  s16x4 lo = *reinterpret_cast<const s16x4*>(p);
  s16x4 hi = *reinterpret_cast<const s16x4*>(p + 16);
  return __builtin_shufflevector(lo, hi, 0, 1, 2, 3, 4, 5, 6, 7);
}
__device__ __forceinline__ s16x8 ldb64pair(const u32* p) {
  s16x4 lo = *reinterpret_cast<const s16x4*>(p);
  s16x4 hi = *reinterpret_cast<const s16x4*>(p + 2);
  return __builtin_shufflevector(lo, hi, 0, 1, 2, 3, 4, 5, 6, 7);
}

// ---------------------------------------------------------------------------
// K0a: w_qkv fp32 -> bf16
// ---------------------------------------------------------------------------
__global__ __launch_bounds__(256) void k0_wcvt(const float* __restrict__ w,
                                               u16* __restrict__ wbf) {
  const int i = (blockIdx.x * 256 + threadIdx.x) * 4;
  f32x4 v = *reinterpret_cast<const f32x4*>(&w[i]);
  u16x4 o;
  o[0] = f2bfu(v[0]); o[1] = f2bfu(v[1]); o[2] = f2bfu(v[2]); o[3] = f2bfu(v[3]);
  *reinterpret_cast<u16x4*>(&wbf[i]) = o;
}

// ---------------------------------------------------------------------------
// K1: qkv[b,o,n] = sum_c wbf[o,c] * x[b,c,n]. Stage x-panel once (de-
// interleaved rows), 3 o-tiles of 128. 8 waves = 4o x 2n; wave = 32o x 64n
// via even/odd col frags -> u32 packed stores (full 128B lines).
// grid (128, 8), 512 thr.
// ---------------------------------------------------------------------------
__global__ __launch_bounds__(512, 4) void k1_qkv(
    const float* __restrict__ x, const u16* __restrict__ wbf,
    u16* __restrict__ qkv) {
  const int n0 = blockIdx.x * 128;
  const int b  = blockIdx.y;
  __shared__ u16 Xs[128 * LTK];
  u32* Xsw = reinterpret_cast<u32*>(Xs);
  const int t = threadIdx.x, lane = t & 63;
  const int wid = t >> 6, wo = wid >> 1, wn = wid & 1;
  const int l31 = lane & 31, g2 = lane >> 5;

  // ---- stage x[c][n0..n0+127] -> Xs[phys(n)][c-pair] (bf16), once ----
  {
    const int nq = t & 31, cr = t >> 5;        // cr 0..15
    const int kpb = cr >> 1;
    const int jh = cr & 1;
    const int prA = 2 * nq + jh;               // phys row of first write
    const int prB = 64 + 2 * nq + jh;          // phys row of second write
    const float* xb = x + (size_t)b * CC * NN + n0 + 4 * nq;
    #pragma unroll 6
    for (int i = 0; i < 12; ++i) {
      f32x4 v = *reinterpret_cast<const f32x4*>(xb + (size_t)(cr + 16 * i) * NN);
      u32 A  = (u32)f2bfu(v[0]) | ((u32)f2bfu(v[1]) << 16);
      u32 Bp = (u32)f2bfu(v[2]) | ((u32)f2bfu(v[3]) << 16);
      u32 oA = __shfl_xor(A, 32);
      u32 oB = __shfl_xor(Bp, 32);
      u32 va, vb;
      if (jh) {
        va = (oB & 0xffffu) | (Bp << 16);
        vb = (oB >> 16) | (Bp & 0xffff0000u);
      } else {
        va = (A & 0xffffu) | (oA << 16);
        vb = (A >> 16) | (oA & 0xffff0000u);
      }
      const int col = kpb + 8 * i;
      Xsw[prA * LTK2 + col] = va;
      Xsw[prB * LTK2 + col] = vb;
    }
  }
  __syncthreads();

  const int nb2 = wn * 32;
  const u32* browE = &Xsw[(nb2 + l31) * LTK2 + 4 * g2];       // even cols
  const u32* browO = &Xsw[(64 + nb2 + l31) * LTK2 + 4 * g2];  // odd cols

  for (int ot = 0; ot < 3; ++ot) {
    const int o0 = ot * 128;
    const u16* wr = wbf + (size_t)(o0 + wo * 32 + l31) * CC + 8 * g2;
    f32x16 accE, accO;
    #pragma unroll
    for (int e = 0; e < 16; ++e) { accE[e] = 0.f; accO[e] = 0.f; }

    s16x8 af0 = *reinterpret_cast<const s16x8*>(wr);
    s16x8 af1 = *reinterpret_cast<const s16x8*>(wr + 16);
    #pragma unroll
    for (int s = 0; s < 6; ++s) {
      s16x8 an0, an1;
      if (s < 5) {
        an0 = *reinterpret_cast<const s16x8*>(wr + (s + 1) * 32);
        an1 = *reinterpret_cast<const s16x8*>(wr + (s + 1) * 32 + 16);
      }
      s16x8 bfE0 = ldb64pair(browE + 16 * s);
      s16x8 bfE1 = ldb64pair(browE + 16 * s + 8);
      s16x8 bfO0 = ldb64pair(browO + 16 * s);
      s16x8 bfO1 = ldb64pair(browO + 16 * s + 8);
      accE = __builtin_amdgcn_mfma_f32_32x32x16_bf16(af0, bfE0, accE, 0, 0, 0);
      accO = __builtin_amdgcn_mfma_f32_32x32x16_bf16(af0, bfO0, accO, 0, 0, 0);
      accE = __builtin_amdgcn_mfma_f32_32x32x16_bf16(af1, bfE1, accE, 0, 0, 0);
      accO = __builtin_amdgcn_mfma_f32_32x32x16_bf16(af1, bfO1, accO, 0, 0, 0);
      af0 = an0; af1 = an1;
    }
    #pragma unroll
    for (int r = 0; r < 16; ++r) {
      const int row = (r & 3) + 8 * (r >> 2) + 4 * g2;
      const u32 pk = (u32)f2bfu(accE[r]) | ((u32)f2bfu(accO[r]) << 16);
      *reinterpret_cast<u32*>(
          &qkv[((size_t)b * C2 + o0 + wo * 32 + row) * NN + n0 + wn * 64 + 2 * l31]) = pk;
    }
  }
}

// ---------------------------------------------------------------------------
// K2: 3x3 depthwise, 8 px/thread (unchanged).
// ---------------------------------------------------------------------------
__global__ __launch_bounds__(256) void k2_dw(
    const u16* __restrict__ qkv, const float* __restrict__ wdw,
    u16* __restrict__ out) {
  const int gid = blockIdx.x;
  const int rb = gid & 7;
  const int plane = gid >> 3;
  const int ch = plane % C2;
  const int t = threadIdx.x;
  const int row = rb * 16 + (t >> 4);
  const int x0 = (t & 15) * 8;
  const u16* p = qkv + (size_t)plane * NN;
  const float* wv = wdw + ch * 9;
  float o[8];
  #pragma unroll
  for (int j = 0; j < 8; ++j) o[j] = 0.f;
  #pragma unroll
  for (int dy = 0; dy < 3; ++dy) {
    const int yy = row + dy - 1;
    if ((unsigned)yy < (unsigned)HH) {
      const u16* rp = p + yy * WW;
      u16x8 m = *reinterpret_cast<const u16x8*>(&rp[x0]);
      float px[10];
      px[0] = (x0 > 0) ? bfu2f(rp[x0 - 1]) : 0.f;
      px[9] = (x0 < 120) ? bfu2f(rp[x0 + 8]) : 0.f;
      #pragma unroll
      for (int j = 0; j < 8; ++j) px[j + 1] = bfu2f(m[j]);
      const float w0 = wv[dy * 3 + 0], w1 = wv[dy * 3 + 1], w2 = wv[dy * 3 + 2];
      #pragma unroll
      for (int j = 0; j < 8; ++j)
        o[j] += w0 * px[j] + w1 * px[j + 1] + w2 * px[j + 2];
    }
  }
  u16x8 ov;
  #pragma unroll
  for (int j = 0; j < 8; ++j) ov[j] = f2bfu(o[j]);
  *reinterpret_cast<u16x8*>(&out[(size_t)plane * NN + row * WW + x0]) = ov;
}

// ---------------------------------------------------------------------------
// K3: partial Gram via MFMA (symmetric; same frag both operands).
// ---------------------------------------------------------------------------
__global__ __launch_bounds__(256) void k3_gram(
    const u16* __restrict__ qkvd, float* __restrict__ gpart) {
  const int bh = blockIdx.x, b = bh >> 2, h = bh & 3;
  const int chunk = blockIdx.y;
  const int t = threadIdx.x, lane = t & 63, wv = t >> 6;
  const int l15 = lane & 15, g = lane >> 4;
  __shared__ float red[4][2304];
  const u16* qb = qkvd + ((size_t)b * C2 + h * HC) * NN;

  f32x4 acc[3][3];
  #pragma unroll
  for (int i = 0; i < 3; ++i)
    #pragma unroll
    for (int j = 0; j < 3; ++j)
      #pragma unroll
      for (int e = 0; e < 4; ++e) acc[i][j][e] = 0.f;

  const int nbase = chunk * 1024 + wv * 256;
  #pragma unroll 2
  for (int st = 0; st < 8; ++st) {
    const int n = nbase + st * 32;
    s16x8 cf[3];
    #pragma unroll
    for (int i = 0; i < 3; ++i)
      cf[i] = ldpair(qb + (size_t)(i * 16 + l15) * NN + n + 4 * g);
    #pragma unroll
    for (int i = 0; i < 3; ++i)
      #pragma unroll
      for (int j = 0; j < 3; ++j)
        acc[i][j] = __builtin_amdgcn_mfma_f32_16x16x32_bf16(cf[i], cf[j], acc[i][j], 0, 0, 0);
  }
  #pragma unroll
  for (int i = 0; i < 3; ++i)
    #pragma unroll
    for (int j = 0; j < 3; ++j)
      #pragma unroll
      for (int r = 0; r < 4; ++r)
        red[wv][(i * 16 + 4 * g + r) * 48 + j * 16 + l15] = acc[i][j][r];
  __syncthreads();
  float* gp = gpart + ((size_t)bh * 16 + chunk) * 2304;
  for (int idx = t; idx < 2304; idx += 256)
    gp[idx] = red[0][idx] + red[1][idx] + red[2][idx] + red[3][idx];
}

// ---------------------------------------------------------------------------
// K4: reduce + normalize + softmax (unchanged)
// ---------------------------------------------------------------------------
__global__ __launch_bounds__(256) void k4_soft(
    const float* __restrict__ gpart, const float* __restrict__ temp,
    float* __restrict__ attn) {
  const int bh = blockIdx.x;
  const int h = bh & 3;
  const int t = threadIdx.x;
  __shared__ float G[2304];
  __shared__ float rn[48];
  for (int idx = t; idx < 2304; idx += 256) {
    float s = 0.f;
    #pragma unroll
    for (int c = 0; c < 16; ++c) s += gpart[((size_t)bh * 16 + c) * 2304 + idx];
    G[idx] = s;
  }
  __syncthreads();
  if (t < 48) rn[t] = rsqrtf(G[t * 48 + t]);
  __syncthreads();
  if (t < 48) {
    const float tm = temp[h];
    float v[48];
    float mx = -1e30f;
    #pragma unroll
    for (int j = 0; j < 48; ++j) {
      v[j] = G[t * 48 + j] * rn[t] * rn[j] * tm;
      mx = fmaxf(mx, v[j]);
    }
    float s = 0.f;
    #pragma unroll
    for (int j = 0; j < 48; ++j) { v[j] = expf(v[j] - mx); s += v[j]; }
    const float inv = 1.f / s;
    #pragma unroll
    for (int j = 0; j < 48; ++j)
      attn[(size_t)bh * 2304 + t * 48 + j] = v[j] * inv;
  }
}

// ---------------------------------------------------------------------------
// K5: M = w_proj x blockdiag(attn) -> bf16 (unchanged)
// ---------------------------------------------------------------------------
__global__ __launch_bounds__(192) void k5_M(
    const float* __restrict__ wproj, const float* __restrict__ attn,
    u16* __restrict__ Mbf) {
  const int o = blockIdx.x;
  const int b = blockIdx.y;
  const int d = threadIdx.x;
  const int h = d / HC, dl = d % HC;
  const float* wrow = wproj + o * CC + h * HC;
  const float* at = attn + ((size_t)(b * NHEADS + h)) * 2304;
  float s = 0.f;
  #pragma unroll
  for (int c = 0; c < HC; ++c) s = fmaf(wrow[c], at[c * HC + dl], s);
  Mbf[((size_t)b * CC + o) * CC + d] = f2bfu(s);
}

// ---------------------------------------------------------------------------
// K6: out[b,o,n] = sum_d Mbf[b,o,d] * v[b,d,n]. Stage v-panel once (de-
// interleaved rows); 3 o-tiles of 64; 4 waves = 2o x 2n; wave = 32o x 64n
// via even/odd col frags -> float2 stores (4 full lines/instr).
// grid (128, 8), 256 thr.
// ---------------------------------------------------------------------------
__global__ __launch_bounds__(256, 4) void k6_out(
    const u16* __restrict__ Mbf, const u16* __restrict__ qkvd,
    float* __restrict__ out) {
  const int n0 = blockIdx.x * 128;
  const int b  = blockIdx.y;
  __shared__ u16 Vs[128 * LTK];
  u32* Vsw = reinterpret_cast<u32*>(Vs);
  const int t = threadIdx.x, lane = t & 63;
  const int wid = t >> 6, wo = wid >> 1, wn = wid & 1;
  const int l31 = lane & 31, g2 = lane >> 5;

  // ---- stage v[d][n0..n0+127] -> Vs[phys(n)][d-pair], once ----
  {
    const int nq = t & 31, cr = t >> 5;        // cr 0..7
    const int kpb = cr >> 1;
    const int jh = cr & 1;
    const int prA = 2 * nq + jh;
    const int prB = 64 + 2 * nq + jh;
    const u16* vbp = qkvd + ((size_t)b * C2 + CC) * NN + n0 + 4 * nq;
    #pragma unroll 6
    for (int i = 0; i < 24; ++i) {
      u16x4 m = *reinterpret_cast<const u16x4*>(vbp + (size_t)(cr + 8 * i) * NN);
      u32 A  = (u32)m[0] | ((u32)m[1] << 16);
      u32 Bp = (u32)m[2] | ((u32)m[3] << 16);
      u32 oA = __shfl_xor(A, 32);
      u32 oB = __shfl_xor(Bp, 32);
      u32 va, vb;
      if (jh) {
        va = (oB & 0xffffu) | (Bp << 16);
        vb = (oB >> 16) | (Bp & 0xffff0000u);
      } else {
        va = (A & 0xffffu) | (oA << 16);
        vb = (A >> 16) | (oA & 0xffff0000u);
      }
      const int col = kpb + 4 * i;
      Vsw[prA * LTK2 + col] = va;
      Vsw[prB * LTK2 + col] = vb;
    }
  }
  __syncthreads();

  const int nb2 = wn * 32;
  const u32* browE = &Vsw[(nb2 + l31) * LTK2 + 4 * g2];
  const u32* browO = &Vsw[(64 + nb2 + l31) * LTK2 + 4 * g2];
  const u16* Ab = Mbf + (size_t)b * CC * CC;

  for (int ot = 0; ot < 3; ++ot) {
    const int o0 = ot * 64;
    const u16* ar = Ab + (size_t)(o0 + wo * 32 + l31) * CC + 8 * g2;
    f32x16 accE, accO;
    #pragma unroll
    for (int e = 0; e < 16; ++e) { accE[e] = 0.f; accO[e] = 0.f; }

    s16x8 af0 = *reinterpret_cast<const s16x8*>(ar);
    s16x8 af1 = *reinterpret_cast<const s16x8*>(ar + 16);
    #pragma unroll
    for (int s = 0; s < 6; ++s) {
      s16x8 an0, an1;
      if (s < 5) {
        an0 = *reinterpret_cast<const s16x8*>(ar + (s + 1) * 32);
        an1 = *reinterpret_cast<const s16x8*>(ar + (s + 1) * 32 + 16);
      }
      s16x8 bfE0 = ldb64pair(browE + 16 * s);
      s16x8 bfE1 = ldb64pair(browE + 16 * s + 8);
      s16x8 bfO0 = ldb64pair(browO + 16 * s);
      s16x8 bfO1 = ldb64pair(browO + 16 * s + 8);
      accE = __builtin_amdgcn_mfma_f32_32x32x16_bf16(af0, bfE0, accE, 0, 0, 0);
      accO = __builtin_amdgcn_mfma_f32_32x32x16_bf16(af0, bfO0, accO, 0, 0, 0);
      accE = __builtin_amdgcn_mfma_f32_32x32x16_bf16(af1, bfE1, accE, 0, 0, 0);
      accO = __builtin_amdgcn_mfma_f32_32x32x16_bf16(af1, bfO1, accO, 0, 0, 0);
      af0 = an0; af1 = an1;
    }
    #pragma unroll
    for (int r = 0; r < 16; ++r) {
      const int row = (r & 3) + 8 * (r >> 2) + 4 * g2;
      float2 st;
      st.x = accE[r];
      st.y = accO[r];
      *reinterpret_cast<float2*>(
          &out[((size_t)b * CC + o0 + wo * 32 + row) * NN + n0 + wn * 64 + 2 * l31]) = st;
    }
  }
}

// ---------------------------------------------------------------------------
extern "C" void kernel_launch(void* const* d_in, const int* in_sizes, int n_in,
                              void* d_out, int out_size, void* d_ws, size_t ws_size,
                              hipStream_t stream) {
  const float* x      = (const float*)d_in[0];
  const float* w_qkv  = (const float*)d_in[1];
  const float* w_dw   = (const float*)d_in[2];
  const float* w_proj = (const float*)d_in[3];
  const float* temp   = (const float*)d_in[4];
  float* out = (float*)d_out;

  const size_t OFF_QKV   = 0;               // bf16  8*384*16384 = 100,663,296
  const size_t OFF_QKVD  = 100663296ULL;    // bf16  same
  const size_t OFF_GPART = 201326592ULL;    // f32   32*16*2304  = 4,718,592
  const size_t OFF_ATTN  = 206045184ULL;    // f32   32*2304     = 294,912
  const size_t OFF_M     = 206340096ULL;    // bf16  8*192*192   = 589,824
  const size_t OFF_WBF   = 206929920ULL;    // bf16  384*192     = 147,456
  const size_t NEEDED    = 207077376ULL;
  if (ws_size < NEEDED) return;

  char* ws = (char*)d_ws;
  u16* qkv   = (u16*)(ws + OFF_QKV);
  u16* qkvd  = (u16*)(ws + OFF_QKVD);
  float* gpart = (float*)(ws + OFF_GPART);
  float* attn  = (float*)(ws + OFF_ATTN);
  u16* Mbf   = (u16*)(ws + OFF_M);
  u16* wbf   = (u16*)(ws + OFF_WBF);

  k0_wcvt<<<dim3(72), 256, 0, stream>>>(w_qkv, wbf);
  k1_qkv <<<dim3(128, 8), 512, 0, stream>>>(x, wbf, qkv);
  k2_dw  <<<dim3(BB * C2 * 8), 256, 0, stream>>>(qkv, w_dw, qkvd);
  k3_gram<<<dim3(BB * NHEADS, 16), 256, 0, stream>>>(qkvd, gpart);
  k4_soft<<<dim3(BB * NHEADS), 256, 0, stream>>>(gpart, temp, attn);
  k5_M   <<<dim3(CC, BB), 192, 0, stream>>>(w_proj, attn, Mbf);
  k6_out <<<dim3(128, 8), 256, 0, stream>>>(Mbf, qkvd, out);
}